// Round 15
// baseline (117.547 us; speedup 1.0000x reference)
//
#include <hip/hip_runtime.h>
#include <hip/hip_fp16.h>
#include <cstdint>
#include <cstddef>

#define DEV __device__ __forceinline__

namespace {

constexpr float SCALE  = 0.35355339059327373f;  // 8^-0.5
constexpr float RATIO  = 63.0f / 127.0f;        // grid->input scale
constexpr float RANGEF = 11.0f;
constexpr float EPS    = 1e-6f;

typedef _Float16 h2 __attribute__((ext_vector_type(2)));

DEV float fdot2(h2 a, h2 b, float c) { return __builtin_amdgcn_fdot2(a, b, c, false); }
DEV h2 pkrtz(float a, float b) {
  auto r = __builtin_amdgcn_cvt_pkrtz(a, b);
  union { decltype(r) i; h2 o; } u; u.i = r; return u.o;
}
DEV h2 permh(unsigned a, unsigned b, unsigned sel) {
  unsigned r = __builtin_amdgcn_perm(a, b, sel);
  union { unsigned u; h2 h; } u; u.u = r; return u.h;
}
DEV void fax(float4& a, float s, const float4& b) {
  a.x = fmaf(s, b.x, a.x); a.y = fmaf(s, b.y, a.y);
  a.z = fmaf(s, b.z, a.z); a.w = fmaf(s, b.w, a.w);
}

// corner weights/indices for one bilinear sample
DEV void corners(float iy, float ix, float* wc, int* idx) {
  float yf = floorf(iy), xf = floorf(ix);
  float wy = iy - yf, wx = ix - xf;
  int y0 = (int)yf, x0 = (int)xf;
  #pragma unroll
  for (int c = 0; c < 4; ++c) {
    int yy = y0 + (c >> 1), xx = x0 + (c & 1);
    bool valid = ((unsigned)yy < 64u) && ((unsigned)xx < 64u);
    float w = ((c >> 1) ? wy : 1.f - wy) * ((c & 1) ? wx : 1.f - wx);
    wc[c] = valid ? w : 0.f;
    idx[c] = valid ? yy * 64 + xx : 0;
  }
}

// ---- transpose x -> vH fp16 (B,4096,128), block 0 also repacks weights -----
__global__ __launch_bounds__(256) void k_transpose(
    const float* __restrict__ x, __half* __restrict__ vH,
    const float* __restrict__ offw, const float* __restrict__ dww,
    const float* __restrict__ wq, const float* __restrict__ wk,
    const float* __restrict__ rpb,
    h2* __restrict__ wT2H, float* __restrict__ dwT,
    h2* __restrict__ wqH, h2* __restrict__ wkH, h2* __restrict__ rpbH) {
  if (blockIdx.x == 0) {
    // wT2H[((tap*2+h)*8 + j2)*9 + i] = h2(offw[(h*9+i)][2j2][tap], ..[2j2+1][tap])
    for (int idx = threadIdx.x; idx < 1296; idx += 256) {
      int t2 = idx / 72, r = idx % 72, j2 = r / 9, i = r % 9;
      int tap = t2 >> 1, h = t2 & 1;
      int o = h * 9 + i;
      wT2H[idx] = pkrtz(offw[o * 144 + (2 * j2) * 9 + tap],
                        offw[o * 144 + (2 * j2 + 1) * 9 + tap]);
    }
    for (int idx = threadIdx.x; idx < 144; idx += 256) {
      int j = idx / 9, tap = idx % 9;
      dwT[tap * 16 + j] = dww[idx];
    }
    // wqH[c2*32+o] = h2(wq[o][2c2], wq[o][2c2+1])
    for (int idx = threadIdx.x; idx < 2048; idx += 256) {
      int c2 = idx >> 5, o = idx & 31;
      wqH[idx] = pkrtz(wq[o * 128 + 2 * c2], wq[o * 128 + 2 * c2 + 1]);
      wkH[idx] = pkrtz(wk[o * 128 + 2 * c2], wk[o * 128 + 2 * c2 + 1]);
    }
    for (int idx = threadIdx.x; idx < 144; idx += 256) {
      int row = idx >> 2, j = idx & 3;
      rpbH[idx] = pkrtz(rpb[row * 8 + 2 * j], rpb[row * 8 + 2 * j + 1]);
    }
  }
  __shared__ float tile[128 * 65];
  int b = blockIdx.x >> 6, y = blockIdx.x & 63;
  const float* xp = x + (size_t)b * 128 * 4096 + (size_t)y * 64;
  int xc = threadIdx.x & 63, cb = threadIdx.x >> 6;
  #pragma unroll
  for (int i = 0; i < 32; ++i) {
    int c = cb * 32 + i;
    tile[c * 65 + xc] = xp[(size_t)c * 4096 + xc];
  }
  __syncthreads();
  int p = threadIdx.x >> 2, c0 = (threadIdx.x & 3) * 32;
  __half* op = vH + ((size_t)b * 4096 + (size_t)y * 64 + p) * 128 + c0;
  #pragma unroll
  for (int i = 0; i < 32; i += 8) {
    union { float4 f; __half2 h[4]; } u;
    #pragma unroll
    for (int j = 0; j < 4; ++j)
      u.h[j] = __floats2half2_rn(tile[(c0 + i + 2 * j) * 65 + p],
                                 tile[(c0 + i + 2 * j + 1) * 65 + p]);
    *(float4*)(op + i) = u.f;
  }
}

// ---- channel-LN + q/k projection (reads vH position-major, fdot2) ----------
__global__ __launch_bounds__(256) void k_lnproj(
    const __half* __restrict__ vH, const float* __restrict__ lnw,
    const float* __restrict__ lnb, const h2* __restrict__ wqH,
    const h2* __restrict__ wkH, float* __restrict__ qT,
    __half* __restrict__ kH) {
  int tid = blockIdx.x * 256 + threadIdx.x;  // [0, B*4096*16)
  int pos = tid >> 4, o4 = tid & 15;         // o4 0-7: q, 8-15: k

  union { uint4 u[16]; h2 h[64]; } xv;
  const uint4* vp = (const uint4*)(vH + (size_t)pos * 128);
  #pragma unroll
  for (int i = 0; i < 16; ++i) xv.u[i] = vp[i];

  float s = 0.f, ss = 0.f;
  #pragma unroll
  for (int i = 0; i < 64; ++i) {
    float fx = (float)xv.h[i][0], fy = (float)xv.h[i][1];
    s += fx + fy;
    ss = fmaf(fx, fx, fmaf(fy, fy, ss));
  }
  float mean = s * (1.f / 128.f);
  float rstd = rsqrtf(ss * (1.f / 128.f) - mean * mean + EPS);

  int isk = o4 >> 3;
  const h2* w = (isk ? wkH : wqH) + (o4 & 7) * 4;
  float a0 = 0.f, a1 = 0.f, a2 = 0.f, a3 = 0.f;
  #pragma unroll 8
  for (int c2 = 0; c2 < 64; ++c2) {
    float v0 = (float)xv.h[c2][0], v1 = (float)xv.h[c2][1];
    float xn0 = (v0 - mean) * rstd * lnw[2 * c2] + lnb[2 * c2];
    float xn1 = (v1 - mean) * rstd * lnw[2 * c2 + 1] + lnb[2 * c2 + 1];
    h2 xh = pkrtz(xn0, xn1);
    const h2* wr = w + c2 * 32;
    a0 = fdot2(xh, wr[0], a0); a1 = fdot2(xh, wr[1], a1);
    a2 = fdot2(xh, wr[2], a2); a3 = fdot2(xh, wr[3], a3);
  }
  if (!isk) {
    *(float4*)(qT + (size_t)pos * 32 + (o4 & 7) * 4) = make_float4(a0, a1, a2, a3);
  } else {
    union { uint2 u; __half2 h[2]; } o;
    o.h[0] = __floats2half2_rn(a0, a1);
    o.h[1] = __floats2half2_rn(a2, a3);
    *(uint2*)(kH + (size_t)pos * 32 + (o4 & 7) * 4) = o.u;
  }
}

// ---- bilinear 64->128 resize -> qrH fp16, pre-scaled by SCALE --------------
// (group-LN in k_dwln is scale-invariant, so dwln consumes the scaled copy)
__global__ __launch_bounds__(256) void k_resize(const float* __restrict__ qT,
                                                __half* __restrict__ qrH) {
  int tid = blockIdx.x * 256 + threadIdx.x;  // [0, np*4)
  int pos = tid >> 2, q4 = tid & 3;
  int b = pos >> 14, rem = pos & 16383;
  int oy = rem >> 7, ox = rem & 127;
  float ys = oy * RATIO, xs = ox * RATIO;
  float yf = floorf(ys), xf = floorf(xs);
  int y0 = (int)yf, x0 = (int)xf;
  int y1 = min(y0 + 1, 63), x1 = min(x0 + 1, 63);
  float wy = ys - yf, wx = xs - xf;
  const float4* p00 = (const float4*)(qT + ((size_t)b * 4096 + y0 * 64 + x0) * 32 + q4 * 8);
  const float4* p01 = (const float4*)(qT + ((size_t)b * 4096 + y0 * 64 + x1) * 32 + q4 * 8);
  const float4* p10 = (const float4*)(qT + ((size_t)b * 4096 + y1 * 64 + x0) * 32 + q4 * 8);
  const float4* p11 = (const float4*)(qT + ((size_t)b * 4096 + y1 * 64 + x1) * 32 + q4 * 8);
  float w00 = (1.f - wy) * (1.f - wx), w01 = (1.f - wy) * wx;
  float w10 = wy * (1.f - wx), w11 = wy * wx;
  float4 r[2];
  #pragma unroll
  for (int i = 0; i < 2; ++i) {
    float4 t = {0.f, 0.f, 0.f, 0.f};
    fax(t, w00, p00[i]); fax(t, w01, p01[i]);
    fax(t, w10, p10[i]); fax(t, w11, p11[i]);
    r[i] = t;
  }
  union { uint4 u; h2 h[4]; } o;
  o.h[0] = pkrtz(r[0].x * SCALE, r[0].y * SCALE);
  o.h[1] = pkrtz(r[0].z * SCALE, r[0].w * SCALE);
  o.h[2] = pkrtz(r[1].x * SCALE, r[1].y * SCALE);
  o.h[3] = pkrtz(r[1].z * SCALE, r[1].w * SCALE);
  *(uint4*)(qrH + (size_t)pos * 32 + q4 * 8) = o.u;
}

// ---- depthwise 3x3 + group-LN + SiLU (fp16 in, scale-invariant) -> tH ------
__global__ __launch_bounds__(256) void k_dwln(
    const __half* __restrict__ qrH, const float* __restrict__ dwT,
    const float* __restrict__ olnw, const float* __restrict__ olnb,
    __half* __restrict__ tH) {
  int tid = blockIdx.x * 256 + threadIdx.x;  // [0, np*4)
  int pos = tid >> 2, sub = tid & 3;         // sub = g*2 + h8
  int b = pos >> 14, rem = pos & 16383;
  int oy = rem >> 7, ox = rem & 127;
  int h8 = sub & 1;
  float a[8] = {};
  #pragma unroll
  for (int kh = 0; kh < 3; ++kh) {
    int ty = oy + kh - 1;
    if ((unsigned)ty >= 128u) continue;
    #pragma unroll
    for (int kw = 0; kw < 3; ++kw) {
      int tx = ox + kw - 1;
      if ((unsigned)tx >= 128u) continue;
      int tap = kh * 3 + kw;
      union { uint4 u; h2 h[4]; } in;
      in.u = *(const uint4*)(qrH +
          ((size_t)b * 16384 + (size_t)ty * 128 + tx) * 32 + sub * 8);
      const float* dw = dwT + tap * 16 + h8 * 8;
      #pragma unroll
      for (int j = 0; j < 4; ++j) {
        a[2 * j]     = fmaf(dw[2 * j],     (float)in.h[j][0], a[2 * j]);
        a[2 * j + 1] = fmaf(dw[2 * j + 1], (float)in.h[j][1], a[2 * j + 1]);
      }
    }
  }
  float s = 0.f, ss = 0.f;
  #pragma unroll
  for (int i = 0; i < 8; ++i) { s += a[i]; ss = fmaf(a[i], a[i], ss); }
  s += __shfl_xor(s, 1);
  ss += __shfl_xor(ss, 1);
  float mean = s * (1.f / 16.f);
  float rstd = rsqrtf(ss * (1.f / 16.f) - mean * mean + EPS);
  const float* ow = olnw + h8 * 8;
  const float* ob = olnb + h8 * 8;
  float r[8];
  #pragma unroll
  for (int i = 0; i < 8; ++i) {
    float t = (a[i] - mean) * rstd * ow[i] + ob[i];
    r[i] = t / (1.f + expf(-t));
  }
  union { uint4 u; h2 h[4]; } o_;
  o_.h[0] = pkrtz(r[0], r[1]); o_.h[1] = pkrtz(r[2], r[3]);
  o_.h[2] = pkrtz(r[4], r[5]); o_.h[3] = pkrtz(r[6], r[7]);
  *(uint4*)(tH + (size_t)pos * 32 + sub * 8) = o_.u;
}

// ---- 16->18 3x3 conv (fp16 in/weights, fdot2) + tanh + abs coords ----------
__global__ __launch_bounds__(256) void k_off(
    const __half* __restrict__ tH, const h2* __restrict__ wT2H,
    const float* __restrict__ offb, float* __restrict__ crd) {
  int tid = blockIdx.x * 128 + (threadIdx.x & 127);  // [0, B*2*16384)
  int h = __builtin_amdgcn_readfirstlane(threadIdx.x >> 7);
  int bg = tid >> 14, rem = tid & 16383;
  int oy = rem >> 7, ox = rem & 127;
  int b = bg >> 1, g = bg & 1;

  float a[9];
  #pragma unroll
  for (int i = 0; i < 9; ++i) a[i] = 0.f;

  #pragma unroll
  for (int kh = 0; kh < 3; ++kh) {
    int ty = oy + kh - 1;
    if (ty < 0 || ty >= 128) continue;
    const __half* base = tH + ((size_t)b * 16384 + (size_t)ty * 128) * 32 + g * 16;
    #pragma unroll
    for (int kw = 0; kw < 3; ++kw) {
      int tap = kh * 3 + kw;
      int tx = ox + kw - 1;
      if ((unsigned)tx >= 128u) continue;
      union { uint4 u[2]; h2 hh[8]; } in;
      const uint4* p = (const uint4*)(base + (size_t)tx * 32);
      in.u[0] = p[0]; in.u[1] = p[1];
      const h2* wrow = wT2H + (size_t)(tap * 2 + h) * 72;
      #pragma unroll
      for (int j2 = 0; j2 < 8; ++j2) {
        h2 f = in.hh[j2];
        #pragma unroll
        for (int i = 0; i < 9; ++i)
          a[i] = fdot2(f, wrow[j2 * 9 + i], a[i]);
      }
    }
  }

  const float* bb = offb + h * 9;
  float* cp = crd + (size_t)tid * 18 + h * 9;
  #pragma unroll
  for (int i = 0; i < 9; ++i) {
    int o = h * 9 + i;
    int kp = o >> 1;
    float basec = (o & 1) ? (float)(kp % 3 - 1 + ox) : (float)(kp / 3 - 1 + oy);
    cp[i] = fmaf(tanhf(a[i] + bb[i]), RANGEF, basec) * RATIO;
  }
}

// ---- FUSED attention v6: qrH pre-scaled fp16, phase A is a raw copy --------
__global__ __launch_bounds__(256) void k_attn2(
    const __half* __restrict__ qrH, const __half* __restrict__ kH,
    const __half* __restrict__ vH, const float* __restrict__ crd,
    const h2* __restrict__ rpbH, float* __restrict__ out) {
  __shared__ __align__(16) h2 qh2S[256];           // 16 pos x 16 h2 (scaled q)
  __shared__ float crdS[576];                      // [g][pos][18]
  __shared__ __align__(16) float4 corn4[576];      // [pos][g][kp][2]
  __shared__ float lgS[576];
  int b = blockIdx.x >> 10;
  int p0 = (blockIdx.x & 1023) * 16;
  const h2* kbase = (const h2*)(kH + (size_t)b * 131072);

  // phase A: stage scaled q (raw 1 KB copy) + crd
  {
    if (threadIdx.x < 64)
      ((uint4*)qh2S)[threadIdx.x] =
          ((const uint4*)(qrH + (size_t)(b * 16384 + p0) * 32))[threadIdx.x];
    if (threadIdx.x < 144) {
      int g = threadIdx.x / 72, i = threadIdx.x - (threadIdx.x / 72) * 72;
      const float4* src = (const float4*)(crd + ((size_t)(b * 2 + g) * 16384 + p0) * 18);
      *(float4*)(crdS + g * 288 + i * 4) = src[i];
    }
  }

  // phase A2 (threads 0..31, barrier-free): kp=8 task per (pos, g).
  if (threadIdx.x < 32) {
    int pl = threadIdx.x >> 1, g = threadIdx.x & 1;
    float2 cc = *(const float2*)(crd +
        ((size_t)(b * 2 + g) * 16384 + p0 + pl) * 18 + 16);
    float wc[4]; int idx[4];
    corners(cc.x, cc.y, wc, idx);

    union { uint4 u[2]; h2 h[8]; } qa;
    const uint4* qg = (const uint4*)(qrH + ((size_t)(b * 16384 + p0 + pl)) * 32 + g * 16);
    qa.u[0] = qg[0]; qa.u[1] = qg[1];

    const h2* kb = kbase + g * 8;
    float a0 = 0.f, a1 = 0.f;
    #pragma unroll
    for (int c = 0; c < 4; ++c) {
      union { float4 f[2]; h2 h[8]; } kk;
      const float4* kr = (const float4*)(kb + (size_t)idx[c] * 16);
      kk.f[0] = kr[0]; kk.f[1] = kr[1];
      float d0 = 0.f, d1 = 0.f;
      #pragma unroll
      for (int j = 0; j < 4; ++j) {
        d0 = fdot2(qa.h[j], kk.h[j], d0);
        d1 = fdot2(qa.h[4 + j], kk.h[4 + j], d1);
      }
      a0 = fmaf(wc[c], d0, a0);
      a1 = fmaf(wc[c], d1, a1);
    }
    const h2* rp0 = rpbH + (2 * g * 9 + 8) * 4;
    const h2* rp1 = rpbH + ((2 * g + 1) * 9 + 8) * 4;
    #pragma unroll
    for (int j = 0; j < 4; ++j) {
      a0 = fdot2(qa.h[j], rp0[j], a0);
      a1 = fdot2(qa.h[4 + j], rp1[j], a1);
    }
    lgS[(pl * 4 + 2 * g) * 9 + 8] = a0;
    lgS[(pl * 4 + 2 * g + 1) * 9 + 8] = a1;
    corn4[((pl * 2 + g) * 9 + 8) * 2 + 0] =
        make_float4(wc[0], __int_as_float(idx[0]), wc[1], __int_as_float(idx[1]));
    corn4[((pl * 2 + g) * 9 + 8) * 2 + 1] =
        make_float4(wc[2], __int_as_float(idx[2]), wc[3], __int_as_float(idx[3]));
  }
  __syncthreads();

  // phase B: exactly 256 tasks = (pos, g, kp 0..7)
  {
    int pl = threadIdx.x >> 4, r = threadIdx.x & 15;
    int g = r >> 3, kp = r & 7;
    float iy = crdS[g * 288 + pl * 18 + 2 * kp];
    float ix = crdS[g * 288 + pl * 18 + 2 * kp + 1];
    float wc[4]; int idx[4];
    corners(iy, ix, wc, idx);

    const h2* qa = qh2S + pl * 16 + g * 8;
    const h2* kb = kbase + g * 8;
    float a0 = 0.f, a1 = 0.f;
    #pragma unroll
    for (int c = 0; c < 4; ++c) {
      union { float4 f[2]; h2 h[8]; } kk;
      const float4* kr = (const float4*)(kb + (size_t)idx[c] * 16);
      kk.f[0] = kr[0]; kk.f[1] = kr[1];
      float d0 = 0.f, d1 = 0.f;
      #pragma unroll
      for (int j = 0; j < 4; ++j) {
        d0 = fdot2(qa[j], kk.h[j], d0);
        d1 = fdot2(qa[4 + j], kk.h[4 + j], d1);
      }
      a0 = fmaf(wc[c], d0, a0);
      a1 = fmaf(wc[c], d1, a1);
    }
    const h2* rp0 = rpbH + (2 * g * 9 + kp) * 4;
    const h2* rp1 = rpbH + ((2 * g + 1) * 9 + kp) * 4;
    #pragma unroll
    for (int j = 0; j < 4; ++j) {
      a0 = fdot2(qa[j], rp0[j], a0);
      a1 = fdot2(qa[4 + j], rp1[j], a1);
    }
    lgS[(pl * 4 + 2 * g) * 9 + kp] = a0;
    lgS[(pl * 4 + 2 * g + 1) * 9 + kp] = a1;
    corn4[((pl * 2 + g) * 9 + kp) * 2 + 0] =
        make_float4(wc[0], __int_as_float(idx[0]), wc[1], __int_as_float(idx[1]));
    corn4[((pl * 2 + g) * 9 + kp) * 2 + 1] =
        make_float4(wc[2], __int_as_float(idx[2]), wc[3], __int_as_float(idx[3]));
  }
  __syncthreads();

  // phase D: per-thread softmax + plain v-gather loop
  int pl = threadIdx.x >> 4, c8 = threadIdx.x & 15;
  int g = c8 >> 3, h = c8 >> 2, ch = c8 * 8;
  int pos = p0 + pl;

  float w9[9];
  {
    const float* l = lgS + (pl * 4 + h) * 9;
    float m = l[0];
    #pragma unroll
    for (int kp = 1; kp < 9; ++kp) m = fmaxf(m, l[kp]);
    float s = 0.f;
    #pragma unroll
    for (int kp = 0; kp < 9; ++kp) { w9[kp] = __expf(l[kp] - m); s += w9[kp]; }
    float inv = 1.f / s;
    #pragma unroll
    for (int kp = 0; kp < 9; ++kp) w9[kp] *= inv;
  }

  const __half* vb = vH + (size_t)b * 524288 + ch;
  const float4* corn = corn4 + (pl * 2 + g) * 18;
  constexpr unsigned SEL_LO = 0x01000504u, SEL_HI = 0x03020706u;

  float acc[8] = {};
  #pragma unroll
  for (int kp = 0; kp < 9; ++kp) {
    float aw = w9[kp];
    float4 ca = corn[kp * 2], cb = corn[kp * 2 + 1];
    #pragma unroll
    for (int pr = 0; pr < 2; ++pr) {
      float4 cp = pr ? cb : ca;
      h2 w01 = pkrtz(aw * cp.x, aw * cp.z);
      uint4 r0 = *(const uint4*)(vb + (size_t)__float_as_int(cp.y) * 128);
      uint4 r1 = *(const uint4*)(vb + (size_t)__float_as_int(cp.w) * 128);
      acc[0] = fdot2(w01, permh(r0.x, r1.x, SEL_LO), acc[0]);
      acc[1] = fdot2(w01, permh(r0.x, r1.x, SEL_HI), acc[1]);
      acc[2] = fdot2(w01, permh(r0.y, r1.y, SEL_LO), acc[2]);
      acc[3] = fdot2(w01, permh(r0.y, r1.y, SEL_HI), acc[3]);
      acc[4] = fdot2(w01, permh(r0.z, r1.z, SEL_LO), acc[4]);
      acc[5] = fdot2(w01, permh(r0.z, r1.z, SEL_HI), acc[5]);
      acc[6] = fdot2(w01, permh(r0.w, r1.w, SEL_LO), acc[6]);
      acc[7] = fdot2(w01, permh(r0.w, r1.w, SEL_HI), acc[7]);
    }
  }

  float* op = out + ((size_t)b * 128 + ch) * 16384 + pos;
  #pragma unroll
  for (int i = 0; i < 8; ++i) op[(size_t)i * 16384] = acc[i];
}

}  // namespace

extern "C" void kernel_launch(void* const* d_in, const int* in_sizes, int n_in,
                              void* d_out, int out_size, void* d_ws, size_t ws_size,
                              hipStream_t stream) {
  const float* x    = (const float*)d_in[0];
  const float* lnw  = (const float*)d_in[1];
  const float* lnb  = (const float*)d_in[2];
  const float* wq   = (const float*)d_in[3];
  const float* wk   = (const float*)d_in[4];
  const float* dww  = (const float*)d_in[5];
  const float* olnw = (const float*)d_in[6];
  const float* olnb = (const float*)d_in[7];
  const float* offw = (const float*)d_in[8];
  const float* offb = (const float*)d_in[9];
  const float* rpb  = (const float*)d_in[10];
  float* outp = (float*)d_out;

  int B = in_sizes[0] / (128 * 64 * 64);
  size_t nb = (size_t)B * 4096;   // input positions
  size_t np = (size_t)B * 16384;  // output positions

  char* w8 = (char*)d_ws;
  __half* vH  = (__half*)w8;  w8 += nb * 128 * 2;
  __half* kH  = (__half*)w8;  w8 += nb * 32 * 2;
  float*  qT  = (float*)w8;   w8 += nb * 32 * 4;
  __half* qrH = (__half*)w8;  w8 += np * 32 * 2;
  __half* tH  = (__half*)w8;  w8 += np * 32 * 2;
  float*  crd = (float*)w8;   w8 += np * 2 * 18 * 4;
  float*  dwT = (float*)w8;   w8 += 144 * 4;
  h2*     wqH = (h2*)w8;      w8 += 2048 * 4;
  h2*     wkH = (h2*)w8;      w8 += 2048 * 4;
  h2*     wT2H= (h2*)w8;      w8 += 1296 * 4;
  h2*     rpbH= (h2*)w8;      w8 += 1024;

  hipLaunchKernelGGL(k_transpose, dim3(B * 64), dim3(256), 0, stream,
                     x, vH, offw, dww, wq, wk, rpb, wT2H, dwT, wqH, wkH, rpbH);
  hipLaunchKernelGGL(k_lnproj, dim3(B * 256), dim3(256), 0, stream,
                     vH, lnw, lnb, wqH, wkH, qT, kH);
  hipLaunchKernelGGL(k_resize, dim3(B * 256), dim3(256), 0, stream, qT, qrH);
  hipLaunchKernelGGL(k_dwln, dim3(B * 256), dim3(256), 0, stream,
                     qrH, dwT, olnw, olnb, tH);
  hipLaunchKernelGGL(k_off, dim3(B * 256), dim3(256), 0, stream, tH, wT2H, offb, crd);
  hipLaunchKernelGGL(k_attn2, dim3(B * 1024), dim3(256), 0, stream,
                     qrH, kH, vH, crd, rpbH, outp);
}

// Round 16
// 102.798 us; speedup vs baseline: 1.1435x; 1.1435x over previous
//
#include <hip/hip_runtime.h>
#include <hip/hip_fp16.h>
#include <cstdint>
#include <cstddef>

#define DEV __device__ __forceinline__

namespace {

constexpr float SCALE  = 0.35355339059327373f;  // 8^-0.5
constexpr float RATIO  = 63.0f / 127.0f;        // grid->input scale
constexpr float RANGEF = 11.0f;
constexpr float EPS    = 1e-6f;

typedef _Float16 h2 __attribute__((ext_vector_type(2)));

DEV float fdot2(h2 a, h2 b, float c) { return __builtin_amdgcn_fdot2(a, b, c, false); }
DEV h2 pkrtz(float a, float b) {
  auto r = __builtin_amdgcn_cvt_pkrtz(a, b);
  union { decltype(r) i; h2 o; } u; u.i = r; return u.o;
}
DEV h2 permh(unsigned a, unsigned b, unsigned sel) {
  unsigned r = __builtin_amdgcn_perm(a, b, sel);
  union { unsigned u; h2 h; } u; u.u = r; return u.h;
}
DEV void fax(float4& a, float s, const float4& b) {
  a.x = fmaf(s, b.x, a.x); a.y = fmaf(s, b.y, a.y);
  a.z = fmaf(s, b.z, a.z); a.w = fmaf(s, b.w, a.w);
}

// corner weights/indices for one bilinear sample
DEV void corners(float iy, float ix, float* wc, int* idx) {
  float yf = floorf(iy), xf = floorf(ix);
  float wy = iy - yf, wx = ix - xf;
  int y0 = (int)yf, x0 = (int)xf;
  #pragma unroll
  for (int c = 0; c < 4; ++c) {
    int yy = y0 + (c >> 1), xx = x0 + (c & 1);
    bool valid = ((unsigned)yy < 64u) && ((unsigned)xx < 64u);
    float w = ((c >> 1) ? wy : 1.f - wy) * ((c & 1) ? wx : 1.f - wx);
    wc[c] = valid ? w : 0.f;
    idx[c] = valid ? yy * 64 + xx : 0;
  }
}

// ---- transpose x -> vH fp16 (B,4096,128), block 0 also repacks weights -----
__global__ __launch_bounds__(256) void k_transpose(
    const float* __restrict__ x, __half* __restrict__ vH,
    const float* __restrict__ offw, const float* __restrict__ dww,
    const float* __restrict__ wq, const float* __restrict__ wk,
    const float* __restrict__ rpb,
    h2* __restrict__ wT2H, float* __restrict__ dwT,
    h2* __restrict__ wqH, h2* __restrict__ wkH, h2* __restrict__ rpbH) {
  if (blockIdx.x == 0) {
    // wT2H[((tap*2+h)*8 + j2)*9 + i] = h2(offw[(h*9+i)][2j2][tap], ..[2j2+1][tap])
    for (int idx = threadIdx.x; idx < 1296; idx += 256) {
      int t2 = idx / 72, r = idx % 72, j2 = r / 9, i = r % 9;
      int tap = t2 >> 1, h = t2 & 1;
      int o = h * 9 + i;
      wT2H[idx] = pkrtz(offw[o * 144 + (2 * j2) * 9 + tap],
                        offw[o * 144 + (2 * j2 + 1) * 9 + tap]);
    }
    for (int idx = threadIdx.x; idx < 144; idx += 256) {
      int j = idx / 9, tap = idx % 9;
      dwT[tap * 16 + j] = dww[idx];
    }
    // wqH[c2*32+o] = h2(wq[o][2c2], wq[o][2c2+1])
    for (int idx = threadIdx.x; idx < 2048; idx += 256) {
      int c2 = idx >> 5, o = idx & 31;
      wqH[idx] = pkrtz(wq[o * 128 + 2 * c2], wq[o * 128 + 2 * c2 + 1]);
      wkH[idx] = pkrtz(wk[o * 128 + 2 * c2], wk[o * 128 + 2 * c2 + 1]);
    }
    for (int idx = threadIdx.x; idx < 144; idx += 256) {
      int row = idx >> 2, j = idx & 3;
      rpbH[idx] = pkrtz(rpb[row * 8 + 2 * j], rpb[row * 8 + 2 * j + 1]);
    }
  }
  __shared__ float tile[128 * 65];
  int b = blockIdx.x >> 6, y = blockIdx.x & 63;
  const float* xp = x + (size_t)b * 128 * 4096 + (size_t)y * 64;
  int xc = threadIdx.x & 63, cb = threadIdx.x >> 6;
  #pragma unroll
  for (int i = 0; i < 32; ++i) {
    int c = cb * 32 + i;
    tile[c * 65 + xc] = xp[(size_t)c * 4096 + xc];
  }
  __syncthreads();
  int p = threadIdx.x >> 2, c0 = (threadIdx.x & 3) * 32;
  __half* op = vH + ((size_t)b * 4096 + (size_t)y * 64 + p) * 128 + c0;
  #pragma unroll
  for (int i = 0; i < 32; i += 8) {
    union { float4 f; __half2 h[4]; } u;
    #pragma unroll
    for (int j = 0; j < 4; ++j)
      u.h[j] = __floats2half2_rn(tile[(c0 + i + 2 * j) * 65 + p],
                                 tile[(c0 + i + 2 * j + 1) * 65 + p]);
    *(float4*)(op + i) = u.f;
  }
}

// ---- channel-LN + q/k projection (vH input, TWO-PASS to avoid spill) -------
__global__ __launch_bounds__(256) void k_lnproj(
    const __half* __restrict__ vH, const float* __restrict__ lnw,
    const float* __restrict__ lnb, const h2* __restrict__ wqH,
    const h2* __restrict__ wkH, float* __restrict__ qT,
    __half* __restrict__ kH) {
  int tid = blockIdx.x * 256 + threadIdx.x;  // [0, B*4096*16)
  int pos = tid >> 4, o4 = tid & 15;         // o4 0-7: q, 8-15: k
  const uint4* vp = (const uint4*)(vH + (size_t)pos * 128);

  // pass 1: stats only (values not kept live)
  float s = 0.f, ss = 0.f;
  #pragma unroll
  for (int i = 0; i < 16; ++i) {
    union { uint4 u; h2 h[4]; } t; t.u = vp[i];
    #pragma unroll
    for (int j = 0; j < 4; ++j) {
      float fx = (float)t.h[j][0], fy = (float)t.h[j][1];
      s += fx + fy;
      ss = fmaf(fx, fx, fmaf(fy, fy, ss));
    }
  }
  float mean = s * (1.f / 128.f);
  float rstd = rsqrtf(ss * (1.f / 128.f) - mean * mean + EPS);

  // forbid CSE of pass-1 loads into pass 2 (would blow registers -> scratch)
  asm volatile("" ::: "memory");

  int isk = o4 >> 3;
  const h2* w = (isk ? wkH : wqH) + (o4 & 7) * 4;
  float a0 = 0.f, a1 = 0.f, a2 = 0.f, a3 = 0.f;
  #pragma unroll
  for (int i = 0; i < 16; ++i) {
    union { uint4 u; h2 h[4]; } t; t.u = vp[i];
    #pragma unroll
    for (int j = 0; j < 4; ++j) {
      int c2 = i * 4 + j;
      float v0 = (float)t.h[j][0], v1 = (float)t.h[j][1];
      float xn0 = (v0 - mean) * rstd * lnw[2 * c2] + lnb[2 * c2];
      float xn1 = (v1 - mean) * rstd * lnw[2 * c2 + 1] + lnb[2 * c2 + 1];
      h2 xh = pkrtz(xn0, xn1);
      const h2* wr = w + c2 * 32;
      a0 = fdot2(xh, wr[0], a0); a1 = fdot2(xh, wr[1], a1);
      a2 = fdot2(xh, wr[2], a2); a3 = fdot2(xh, wr[3], a3);
    }
  }
  if (!isk) {
    *(float4*)(qT + (size_t)pos * 32 + (o4 & 7) * 4) = make_float4(a0, a1, a2, a3);
  } else {
    union { uint2 u; __half2 h[2]; } o;
    o.h[0] = __floats2half2_rn(a0, a1);
    o.h[1] = __floats2half2_rn(a2, a3);
    *(uint2*)(kH + (size_t)pos * 32 + (o4 & 7) * 4) = o.u;
  }
}

// ---- bilinear 64->128 resize -> qrH fp16, pre-scaled by SCALE --------------
// (group-LN in k_dwln is scale-invariant, so dwln consumes the scaled copy)
__global__ __launch_bounds__(256) void k_resize(const float* __restrict__ qT,
                                                __half* __restrict__ qrH) {
  int tid = blockIdx.x * 256 + threadIdx.x;  // [0, np*4)
  int pos = tid >> 2, q4 = tid & 3;
  int b = pos >> 14, rem = pos & 16383;
  int oy = rem >> 7, ox = rem & 127;
  float ys = oy * RATIO, xs = ox * RATIO;
  float yf = floorf(ys), xf = floorf(xs);
  int y0 = (int)yf, x0 = (int)xf;
  int y1 = min(y0 + 1, 63), x1 = min(x0 + 1, 63);
  float wy = ys - yf, wx = xs - xf;
  const float4* p00 = (const float4*)(qT + ((size_t)b * 4096 + y0 * 64 + x0) * 32 + q4 * 8);
  const float4* p01 = (const float4*)(qT + ((size_t)b * 4096 + y0 * 64 + x1) * 32 + q4 * 8);
  const float4* p10 = (const float4*)(qT + ((size_t)b * 4096 + y1 * 64 + x0) * 32 + q4 * 8);
  const float4* p11 = (const float4*)(qT + ((size_t)b * 4096 + y1 * 64 + x1) * 32 + q4 * 8);
  float w00 = (1.f - wy) * (1.f - wx), w01 = (1.f - wy) * wx;
  float w10 = wy * (1.f - wx), w11 = wy * wx;
  float4 r[2];
  #pragma unroll
  for (int i = 0; i < 2; ++i) {
    float4 t = {0.f, 0.f, 0.f, 0.f};
    fax(t, w00, p00[i]); fax(t, w01, p01[i]);
    fax(t, w10, p10[i]); fax(t, w11, p11[i]);
    r[i] = t;
  }
  union { uint4 u; h2 h[4]; } o;
  o.h[0] = pkrtz(r[0].x * SCALE, r[0].y * SCALE);
  o.h[1] = pkrtz(r[0].z * SCALE, r[0].w * SCALE);
  o.h[2] = pkrtz(r[1].x * SCALE, r[1].y * SCALE);
  o.h[3] = pkrtz(r[1].z * SCALE, r[1].w * SCALE);
  *(uint4*)(qrH + (size_t)pos * 32 + q4 * 8) = o.u;
}

// ---- depthwise 3x3 + group-LN + SiLU (fp16 in, scale-invariant) -> tH ------
__global__ __launch_bounds__(256) void k_dwln(
    const __half* __restrict__ qrH, const float* __restrict__ dwT,
    const float* __restrict__ olnw, const float* __restrict__ olnb,
    __half* __restrict__ tH) {
  int tid = blockIdx.x * 256 + threadIdx.x;  // [0, np*4)
  int pos = tid >> 2, sub = tid & 3;         // sub = g*2 + h8
  int b = pos >> 14, rem = pos & 16383;
  int oy = rem >> 7, ox = rem & 127;
  int h8 = sub & 1;
  float a[8] = {};
  #pragma unroll
  for (int kh = 0; kh < 3; ++kh) {
    int ty = oy + kh - 1;
    if ((unsigned)ty >= 128u) continue;
    #pragma unroll
    for (int kw = 0; kw < 3; ++kw) {
      int tx = ox + kw - 1;
      if ((unsigned)tx >= 128u) continue;
      int tap = kh * 3 + kw;
      union { uint4 u; h2 h[4]; } in;
      in.u = *(const uint4*)(qrH +
          ((size_t)b * 16384 + (size_t)ty * 128 + tx) * 32 + sub * 8);
      const float* dw = dwT + tap * 16 + h8 * 8;
      #pragma unroll
      for (int j = 0; j < 4; ++j) {
        a[2 * j]     = fmaf(dw[2 * j],     (float)in.h[j][0], a[2 * j]);
        a[2 * j + 1] = fmaf(dw[2 * j + 1], (float)in.h[j][1], a[2 * j + 1]);
      }
    }
  }
  float s = 0.f, ss = 0.f;
  #pragma unroll
  for (int i = 0; i < 8; ++i) { s += a[i]; ss = fmaf(a[i], a[i], ss); }
  s += __shfl_xor(s, 1);
  ss += __shfl_xor(ss, 1);
  float mean = s * (1.f / 16.f);
  float rstd = rsqrtf(ss * (1.f / 16.f) - mean * mean + EPS);
  const float* ow = olnw + h8 * 8;
  const float* ob = olnb + h8 * 8;
  float r[8];
  #pragma unroll
  for (int i = 0; i < 8; ++i) {
    float t = (a[i] - mean) * rstd * ow[i] + ob[i];
    r[i] = t / (1.f + expf(-t));
  }
  union { uint4 u; h2 h[4]; } o_;
  o_.h[0] = pkrtz(r[0], r[1]); o_.h[1] = pkrtz(r[2], r[3]);
  o_.h[2] = pkrtz(r[4], r[5]); o_.h[3] = pkrtz(r[6], r[7]);
  *(uint4*)(tH + (size_t)pos * 32 + sub * 8) = o_.u;
}

// ---- 16->18 3x3 conv (fp16 in/weights, fdot2) + tanh + abs coords ----------
__global__ __launch_bounds__(256) void k_off(
    const __half* __restrict__ tH, const h2* __restrict__ wT2H,
    const float* __restrict__ offb, float* __restrict__ crd) {
  int tid = blockIdx.x * 128 + (threadIdx.x & 127);  // [0, B*2*16384)
  int h = __builtin_amdgcn_readfirstlane(threadIdx.x >> 7);
  int bg = tid >> 14, rem = tid & 16383;
  int oy = rem >> 7, ox = rem & 127;
  int b = bg >> 1, g = bg & 1;

  float a[9];
  #pragma unroll
  for (int i = 0; i < 9; ++i) a[i] = 0.f;

  #pragma unroll
  for (int kh = 0; kh < 3; ++kh) {
    int ty = oy + kh - 1;
    if (ty < 0 || ty >= 128) continue;
    const __half* base = tH + ((size_t)b * 16384 + (size_t)ty * 128) * 32 + g * 16;
    #pragma unroll
    for (int kw = 0; kw < 3; ++kw) {
      int tap = kh * 3 + kw;
      int tx = ox + kw - 1;
      if ((unsigned)tx >= 128u) continue;
      union { uint4 u[2]; h2 hh[8]; } in;
      const uint4* p = (const uint4*)(base + (size_t)tx * 32);
      in.u[0] = p[0]; in.u[1] = p[1];
      const h2* wrow = wT2H + (size_t)(tap * 2 + h) * 72;
      #pragma unroll
      for (int j2 = 0; j2 < 8; ++j2) {
        h2 f = in.hh[j2];
        #pragma unroll
        for (int i = 0; i < 9; ++i)
          a[i] = fdot2(f, wrow[j2 * 9 + i], a[i]);
      }
    }
  }

  const float* bb = offb + h * 9;
  float* cp = crd + (size_t)tid * 18 + h * 9;
  #pragma unroll
  for (int i = 0; i < 9; ++i) {
    int o = h * 9 + i;
    int kp = o >> 1;
    float basec = (o & 1) ? (float)(kp % 3 - 1 + ox) : (float)(kp / 3 - 1 + oy);
    cp[i] = fmaf(tanhf(a[i] + bb[i]), RANGEF, basec) * RATIO;
  }
}

// ---- FUSED attention v6: qrH pre-scaled fp16, phase A is a raw copy --------
__global__ __launch_bounds__(256) void k_attn2(
    const __half* __restrict__ qrH, const __half* __restrict__ kH,
    const __half* __restrict__ vH, const float* __restrict__ crd,
    const h2* __restrict__ rpbH, float* __restrict__ out) {
  __shared__ __align__(16) h2 qh2S[256];           // 16 pos x 16 h2 (scaled q)
  __shared__ float crdS[576];                      // [g][pos][18]
  __shared__ __align__(16) float4 corn4[576];      // [pos][g][kp][2]
  __shared__ float lgS[576];
  int b = blockIdx.x >> 10;
  int p0 = (blockIdx.x & 1023) * 16;
  const h2* kbase = (const h2*)(kH + (size_t)b * 131072);

  // phase A: stage scaled q (raw 1 KB copy) + crd
  {
    if (threadIdx.x < 64)
      ((uint4*)qh2S)[threadIdx.x] =
          ((const uint4*)(qrH + (size_t)(b * 16384 + p0) * 32))[threadIdx.x];
    if (threadIdx.x < 144) {
      int g = threadIdx.x / 72, i = threadIdx.x - (threadIdx.x / 72) * 72;
      const float4* src = (const float4*)(crd + ((size_t)(b * 2 + g) * 16384 + p0) * 18);
      *(float4*)(crdS + g * 288 + i * 4) = src[i];
    }
  }

  // phase A2 (threads 0..31, barrier-free): kp=8 task per (pos, g).
  if (threadIdx.x < 32) {
    int pl = threadIdx.x >> 1, g = threadIdx.x & 1;
    float2 cc = *(const float2*)(crd +
        ((size_t)(b * 2 + g) * 16384 + p0 + pl) * 18 + 16);
    float wc[4]; int idx[4];
    corners(cc.x, cc.y, wc, idx);

    union { uint4 u[2]; h2 h[8]; } qa;
    const uint4* qg = (const uint4*)(qrH + ((size_t)(b * 16384 + p0 + pl)) * 32 + g * 16);
    qa.u[0] = qg[0]; qa.u[1] = qg[1];

    const h2* kb = kbase + g * 8;
    float a0 = 0.f, a1 = 0.f;
    #pragma unroll
    for (int c = 0; c < 4; ++c) {
      union { float4 f[2]; h2 h[8]; } kk;
      const float4* kr = (const float4*)(kb + (size_t)idx[c] * 16);
      kk.f[0] = kr[0]; kk.f[1] = kr[1];
      float d0 = 0.f, d1 = 0.f;
      #pragma unroll
      for (int j = 0; j < 4; ++j) {
        d0 = fdot2(qa.h[j], kk.h[j], d0);
        d1 = fdot2(qa.h[4 + j], kk.h[4 + j], d1);
      }
      a0 = fmaf(wc[c], d0, a0);
      a1 = fmaf(wc[c], d1, a1);
    }
    const h2* rp0 = rpbH + (2 * g * 9 + 8) * 4;
    const h2* rp1 = rpbH + ((2 * g + 1) * 9 + 8) * 4;
    #pragma unroll
    for (int j = 0; j < 4; ++j) {
      a0 = fdot2(qa.h[j], rp0[j], a0);
      a1 = fdot2(qa.h[4 + j], rp1[j], a1);
    }
    lgS[(pl * 4 + 2 * g) * 9 + 8] = a0;
    lgS[(pl * 4 + 2 * g + 1) * 9 + 8] = a1;
    corn4[((pl * 2 + g) * 9 + 8) * 2 + 0] =
        make_float4(wc[0], __int_as_float(idx[0]), wc[1], __int_as_float(idx[1]));
    corn4[((pl * 2 + g) * 9 + 8) * 2 + 1] =
        make_float4(wc[2], __int_as_float(idx[2]), wc[3], __int_as_float(idx[3]));
  }
  __syncthreads();

  // phase B: exactly 256 tasks = (pos, g, kp 0..7)
  {
    int pl = threadIdx.x >> 4, r = threadIdx.x & 15;
    int g = r >> 3, kp = r & 7;
    float iy = crdS[g * 288 + pl * 18 + 2 * kp];
    float ix = crdS[g * 288 + pl * 18 + 2 * kp + 1];
    float wc[4]; int idx[4];
    corners(iy, ix, wc, idx);

    const h2* qa = qh2S + pl * 16 + g * 8;
    const h2* kb = kbase + g * 8;
    float a0 = 0.f, a1 = 0.f;
    #pragma unroll
    for (int c = 0; c < 4; ++c) {
      union { float4 f[2]; h2 h[8]; } kk;
      const float4* kr = (const float4*)(kb + (size_t)idx[c] * 16);
      kk.f[0] = kr[0]; kk.f[1] = kr[1];
      float d0 = 0.f, d1 = 0.f;
      #pragma unroll
      for (int j = 0; j < 4; ++j) {
        d0 = fdot2(qa[j], kk.h[j], d0);
        d1 = fdot2(qa[4 + j], kk.h[4 + j], d1);
      }
      a0 = fmaf(wc[c], d0, a0);
      a1 = fmaf(wc[c], d1, a1);
    }
    const h2* rp0 = rpbH + (2 * g * 9 + kp) * 4;
    const h2* rp1 = rpbH + ((2 * g + 1) * 9 + kp) * 4;
    #pragma unroll
    for (int j = 0; j < 4; ++j) {
      a0 = fdot2(qa[j], rp0[j], a0);
      a1 = fdot2(qa[4 + j], rp1[j], a1);
    }
    lgS[(pl * 4 + 2 * g) * 9 + kp] = a0;
    lgS[(pl * 4 + 2 * g + 1) * 9 + kp] = a1;
    corn4[((pl * 2 + g) * 9 + kp) * 2 + 0] =
        make_float4(wc[0], __int_as_float(idx[0]), wc[1], __int_as_float(idx[1]));
    corn4[((pl * 2 + g) * 9 + kp) * 2 + 1] =
        make_float4(wc[2], __int_as_float(idx[2]), wc[3], __int_as_float(idx[3]));
  }
  __syncthreads();

  // phase D: per-thread softmax + plain v-gather loop
  int pl = threadIdx.x >> 4, c8 = threadIdx.x & 15;
  int g = c8 >> 3, h = c8 >> 2, ch = c8 * 8;
  int pos = p0 + pl;

  float w9[9];
  {
    const float* l = lgS + (pl * 4 + h) * 9;
    float m = l[0];
    #pragma unroll
    for (int kp = 1; kp < 9; ++kp) m = fmaxf(m, l[kp]);
    float s = 0.f;
    #pragma unroll
    for (int kp = 0; kp < 9; ++kp) { w9[kp] = __expf(l[kp] - m); s += w9[kp]; }
    float inv = 1.f / s;
    #pragma unroll
    for (int kp = 0; kp < 9; ++kp) w9[kp] *= inv;
  }

  const __half* vb = vH + (size_t)b * 524288 + ch;
  const float4* corn = corn4 + (pl * 2 + g) * 18;
  constexpr unsigned SEL_LO = 0x01000504u, SEL_HI = 0x03020706u;

  float acc[8] = {};
  #pragma unroll
  for (int kp = 0; kp < 9; ++kp) {
    float aw = w9[kp];
    float4 ca = corn[kp * 2], cb = corn[kp * 2 + 1];
    #pragma unroll
    for (int pr = 0; pr < 2; ++pr) {
      float4 cp = pr ? cb : ca;
      h2 w01 = pkrtz(aw * cp.x, aw * cp.z);
      uint4 r0 = *(const uint4*)(vb + (size_t)__float_as_int(cp.y) * 128);
      uint4 r1 = *(const uint4*)(vb + (size_t)__float_as_int(cp.w) * 128);
      acc[0] = fdot2(w01, permh(r0.x, r1.x, SEL_LO), acc[0]);
      acc[1] = fdot2(w01, permh(r0.x, r1.x, SEL_HI), acc[1]);
      acc[2] = fdot2(w01, permh(r0.y, r1.y, SEL_LO), acc[2]);
      acc[3] = fdot2(w01, permh(r0.y, r1.y, SEL_HI), acc[3]);
      acc[4] = fdot2(w01, permh(r0.z, r1.z, SEL_LO), acc[4]);
      acc[5] = fdot2(w01, permh(r0.z, r1.z, SEL_HI), acc[5]);
      acc[6] = fdot2(w01, permh(r0.w, r1.w, SEL_LO), acc[6]);
      acc[7] = fdot2(w01, permh(r0.w, r1.w, SEL_HI), acc[7]);
    }
  }

  float* op = out + ((size_t)b * 128 + ch) * 16384 + pos;
  #pragma unroll
  for (int i = 0; i < 8; ++i) op[(size_t)i * 16384] = acc[i];
}

}  // namespace

extern "C" void kernel_launch(void* const* d_in, const int* in_sizes, int n_in,
                              void* d_out, int out_size, void* d_ws, size_t ws_size,
                              hipStream_t stream) {
  const float* x    = (const float*)d_in[0];
  const float* lnw  = (const float*)d_in[1];
  const float* lnb  = (const float*)d_in[2];
  const float* wq   = (const float*)d_in[3];
  const float* wk   = (const float*)d_in[4];
  const float* dww  = (const float*)d_in[5];
  const float* olnw = (const float*)d_in[6];
  const float* olnb = (const float*)d_in[7];
  const float* offw = (const float*)d_in[8];
  const float* offb = (const float*)d_in[9];
  const float* rpb  = (const float*)d_in[10];
  float* outp = (float*)d_out;

  int B = in_sizes[0] / (128 * 64 * 64);
  size_t nb = (size_t)B * 4096;   // input positions
  size_t np = (size_t)B * 16384;  // output positions

  char* w8 = (char*)d_ws;
  __half* vH  = (__half*)w8;  w8 += nb * 128 * 2;
  __half* kH  = (__half*)w8;  w8 += nb * 32 * 2;
  float*  qT  = (float*)w8;   w8 += nb * 32 * 4;
  __half* qrH = (__half*)w8;  w8 += np * 32 * 2;
  __half* tH  = (__half*)w8;  w8 += np * 32 * 2;
  float*  crd = (float*)w8;   w8 += np * 2 * 18 * 4;
  float*  dwT = (float*)w8;   w8 += 144 * 4;
  h2*     wqH = (h2*)w8;      w8 += 2048 * 4;
  h2*     wkH = (h2*)w8;      w8 += 2048 * 4;
  h2*     wT2H= (h2*)w8;      w8 += 1296 * 4;
  h2*     rpbH= (h2*)w8;      w8 += 1024;

  hipLaunchKernelGGL(k_transpose, dim3(B * 64), dim3(256), 0, stream,
                     x, vH, offw, dww, wq, wk, rpb, wT2H, dwT, wqH, wkH, rpbH);
  hipLaunchKernelGGL(k_lnproj, dim3(B * 256), dim3(256), 0, stream,
                     vH, lnw, lnb, wqH, wkH, qT, kH);
  hipLaunchKernelGGL(k_resize, dim3(B * 256), dim3(256), 0, stream, qT, qrH);
  hipLaunchKernelGGL(k_dwln, dim3(B * 256), dim3(256), 0, stream,
                     qrH, dwT, olnw, olnb, tH);
  hipLaunchKernelGGL(k_off, dim3(B * 256), dim3(256), 0, stream, tH, wT2H, offb, crd);
  hipLaunchKernelGGL(k_attn2, dim3(B * 1024), dim3(256), 0, stream,
                     qrH, kH, vH, crd, rpbH, outp);
}

// Round 17
// 102.554 us; speedup vs baseline: 1.1462x; 1.0024x over previous
//
#include <hip/hip_runtime.h>
#include <hip/hip_fp16.h>
#include <cstdint>
#include <cstddef>

#define DEV __device__ __forceinline__

namespace {

constexpr float SCALE  = 0.35355339059327373f;  // 8^-0.5
constexpr float RATIO  = 63.0f / 127.0f;        // grid->input scale
constexpr float RANGEF = 11.0f;
constexpr float EPS    = 1e-6f;

typedef _Float16 h2 __attribute__((ext_vector_type(2)));

DEV float fdot2(h2 a, h2 b, float c) { return __builtin_amdgcn_fdot2(a, b, c, false); }
DEV h2 pkrtz(float a, float b) {
  auto r = __builtin_amdgcn_cvt_pkrtz(a, b);
  union { decltype(r) i; h2 o; } u; u.i = r; return u.o;
}
DEV h2 permh(unsigned a, unsigned b, unsigned sel) {
  unsigned r = __builtin_amdgcn_perm(a, b, sel);
  union { unsigned u; h2 h; } u; u.u = r; return u.h;
}

// corner weights/indices for one bilinear sample
DEV void corners(float iy, float ix, float* wc, int* idx) {
  float yf = floorf(iy), xf = floorf(ix);
  float wy = iy - yf, wx = ix - xf;
  int y0 = (int)yf, x0 = (int)xf;
  #pragma unroll
  for (int c = 0; c < 4; ++c) {
    int yy = y0 + (c >> 1), xx = x0 + (c & 1);
    bool valid = ((unsigned)yy < 64u) && ((unsigned)xx < 64u);
    float w = ((c >> 1) ? wy : 1.f - wy) * ((c & 1) ? wx : 1.f - wx);
    wc[c] = valid ? w : 0.f;
    idx[c] = valid ? yy * 64 + xx : 0;
  }
}

// ---- transpose x -> vH fp16 (B,4096,128), block 0 also repacks weights -----
__global__ __launch_bounds__(256) void k_transpose(
    const float* __restrict__ x, __half* __restrict__ vH,
    const float* __restrict__ offw, const float* __restrict__ dww,
    const float* __restrict__ wq, const float* __restrict__ wk,
    const float* __restrict__ rpb,
    h2* __restrict__ wT2H, float* __restrict__ dwT,
    h2* __restrict__ wqH, h2* __restrict__ wkH, h2* __restrict__ rpbH) {
  if (blockIdx.x == 0) {
    // wT2H[((tap*2+h)*8 + j2)*9 + i] = h2(offw[(h*9+i)][2j2][tap], ..[2j2+1][tap])
    for (int idx = threadIdx.x; idx < 1296; idx += 256) {
      int t2 = idx / 72, r = idx % 72, j2 = r / 9, i = r % 9;
      int tap = t2 >> 1, h = t2 & 1;
      int o = h * 9 + i;
      wT2H[idx] = pkrtz(offw[o * 144 + (2 * j2) * 9 + tap],
                        offw[o * 144 + (2 * j2 + 1) * 9 + tap]);
    }
    for (int idx = threadIdx.x; idx < 144; idx += 256) {
      int j = idx / 9, tap = idx % 9;
      dwT[tap * 16 + j] = dww[idx];
    }
    // wqH[c2*32+o] = h2(wq[o][2c2], wq[o][2c2+1])
    for (int idx = threadIdx.x; idx < 2048; idx += 256) {
      int c2 = idx >> 5, o = idx & 31;
      wqH[idx] = pkrtz(wq[o * 128 + 2 * c2], wq[o * 128 + 2 * c2 + 1]);
      wkH[idx] = pkrtz(wk[o * 128 + 2 * c2], wk[o * 128 + 2 * c2 + 1]);
    }
    for (int idx = threadIdx.x; idx < 144; idx += 256) {
      int row = idx >> 2, j = idx & 3;
      rpbH[idx] = pkrtz(rpb[row * 8 + 2 * j], rpb[row * 8 + 2 * j + 1]);
    }
  }
  __shared__ float tile[128 * 65];
  int b = blockIdx.x >> 6, y = blockIdx.x & 63;
  const float* xp = x + (size_t)b * 128 * 4096 + (size_t)y * 64;
  int xc = threadIdx.x & 63, cb = threadIdx.x >> 6;
  #pragma unroll
  for (int i = 0; i < 32; ++i) {
    int c = cb * 32 + i;
    tile[c * 65 + xc] = xp[(size_t)c * 4096 + xc];
  }
  __syncthreads();
  int p = threadIdx.x >> 2, c0 = (threadIdx.x & 3) * 32;
  __half* op = vH + ((size_t)b * 4096 + (size_t)y * 64 + p) * 128 + c0;
  #pragma unroll
  for (int i = 0; i < 32; i += 8) {
    union { float4 f; __half2 h[4]; } u;
    #pragma unroll
    for (int j = 0; j < 4; ++j)
      u.h[j] = __floats2half2_rn(tile[(c0 + i + 2 * j) * 65 + p],
                                 tile[(c0 + i + 2 * j + 1) * 65 + p]);
    *(float4*)(op + i) = u.f;
  }
}

// ---- channel-LN + q/k projection (vH input, TWO-PASS, fp16 outputs) --------
__global__ __launch_bounds__(256) void k_lnproj(
    const __half* __restrict__ vH, const float* __restrict__ lnw,
    const float* __restrict__ lnb, const h2* __restrict__ wqH,
    const h2* __restrict__ wkH, __half* __restrict__ qH,
    __half* __restrict__ kH) {
  int tid = blockIdx.x * 256 + threadIdx.x;  // [0, B*4096*16)
  int pos = tid >> 4, o4 = tid & 15;         // o4 0-7: q, 8-15: k
  const uint4* vp = (const uint4*)(vH + (size_t)pos * 128);

  // pass 1: stats only (values not kept live)
  float s = 0.f, ss = 0.f;
  #pragma unroll
  for (int i = 0; i < 16; ++i) {
    union { uint4 u; h2 h[4]; } t; t.u = vp[i];
    #pragma unroll
    for (int j = 0; j < 4; ++j) {
      float fx = (float)t.h[j][0], fy = (float)t.h[j][1];
      s += fx + fy;
      ss = fmaf(fx, fx, fmaf(fy, fy, ss));
    }
  }
  float mean = s * (1.f / 128.f);
  float rstd = rsqrtf(ss * (1.f / 128.f) - mean * mean + EPS);

  // forbid CSE of pass-1 loads into pass 2 (would blow registers -> scratch)
  asm volatile("" ::: "memory");

  int isk = o4 >> 3;
  const h2* w = (isk ? wkH : wqH) + (o4 & 7) * 4;
  float a0 = 0.f, a1 = 0.f, a2 = 0.f, a3 = 0.f;
  #pragma unroll
  for (int i = 0; i < 16; ++i) {
    union { uint4 u; h2 h[4]; } t; t.u = vp[i];
    #pragma unroll
    for (int j = 0; j < 4; ++j) {
      int c2 = i * 4 + j;
      float v0 = (float)t.h[j][0], v1 = (float)t.h[j][1];
      float xn0 = (v0 - mean) * rstd * lnw[2 * c2] + lnb[2 * c2];
      float xn1 = (v1 - mean) * rstd * lnw[2 * c2 + 1] + lnb[2 * c2 + 1];
      h2 xh = pkrtz(xn0, xn1);
      const h2* wr = w + c2 * 32;
      a0 = fdot2(xh, wr[0], a0); a1 = fdot2(xh, wr[1], a1);
      a2 = fdot2(xh, wr[2], a2); a3 = fdot2(xh, wr[3], a3);
    }
  }
  union { uint2 u; __half2 h[2]; } o;
  o.h[0] = __floats2half2_rn(a0, a1);
  o.h[1] = __floats2half2_rn(a2, a3);
  __half* dst = (isk ? kH : qH) + (size_t)pos * 32 + (o4 & 7) * 4;
  *(uint2*)dst = o.u;
}

// ---- bilinear 64->128 resize (fp16 in) -> qrH fp16, pre-scaled by SCALE ----
__global__ __launch_bounds__(256) void k_resize(const __half* __restrict__ qH,
                                                __half* __restrict__ qrH) {
  int tid = blockIdx.x * 256 + threadIdx.x;  // [0, np*4)
  int pos = tid >> 2, q4 = tid & 3;
  int b = pos >> 14, rem = pos & 16383;
  int oy = rem >> 7, ox = rem & 127;
  float ys = oy * RATIO, xs = ox * RATIO;
  float yf = floorf(ys), xf = floorf(xs);
  int y0 = (int)yf, x0 = (int)xf;
  int y1 = min(y0 + 1, 63), x1 = min(x0 + 1, 63);
  float wy = ys - yf, wx = xs - xf;
  const __half* base = qH + (size_t)b * 131072 + q4 * 8;
  union { uint4 u; h2 h[4]; } c00, c01, c10, c11;
  c00.u = *(const uint4*)(base + (size_t)(y0 * 64 + x0) * 32);
  c01.u = *(const uint4*)(base + (size_t)(y0 * 64 + x1) * 32);
  c10.u = *(const uint4*)(base + (size_t)(y1 * 64 + x0) * 32);
  c11.u = *(const uint4*)(base + (size_t)(y1 * 64 + x1) * 32);
  float w00 = (1.f - wy) * (1.f - wx) * SCALE, w01 = (1.f - wy) * wx * SCALE;
  float w10 = wy * (1.f - wx) * SCALE, w11 = wy * wx * SCALE;
  union { uint4 u; h2 h[4]; } o;
  #pragma unroll
  for (int j = 0; j < 4; ++j) {
    float r0 = w00 * (float)c00.h[j][0] + w01 * (float)c01.h[j][0] +
               w10 * (float)c10.h[j][0] + w11 * (float)c11.h[j][0];
    float r1 = w00 * (float)c00.h[j][1] + w01 * (float)c01.h[j][1] +
               w10 * (float)c10.h[j][1] + w11 * (float)c11.h[j][1];
    o.h[j] = pkrtz(r0, r1);
  }
  *(uint4*)(qrH + (size_t)pos * 32 + q4 * 8) = o.u;
}

// ---- depthwise 3x3 + group-LN + SiLU (fp16 in, scale-invariant) -> tH ------
__global__ __launch_bounds__(256) void k_dwln(
    const __half* __restrict__ qrH, const float* __restrict__ dwT,
    const float* __restrict__ olnw, const float* __restrict__ olnb,
    __half* __restrict__ tH) {
  int tid = blockIdx.x * 256 + threadIdx.x;  // [0, np*4)
  int pos = tid >> 2, sub = tid & 3;         // sub = g*2 + h8
  int b = pos >> 14, rem = pos & 16383;
  int oy = rem >> 7, ox = rem & 127;
  int h8 = sub & 1;
  float a[8] = {};
  #pragma unroll
  for (int kh = 0; kh < 3; ++kh) {
    int ty = oy + kh - 1;
    if ((unsigned)ty >= 128u) continue;
    #pragma unroll
    for (int kw = 0; kw < 3; ++kw) {
      int tx = ox + kw - 1;
      if ((unsigned)tx >= 128u) continue;
      int tap = kh * 3 + kw;
      union { uint4 u; h2 h[4]; } in;
      in.u = *(const uint4*)(qrH +
          ((size_t)b * 16384 + (size_t)ty * 128 + tx) * 32 + sub * 8);
      const float* dw = dwT + tap * 16 + h8 * 8;
      #pragma unroll
      for (int j = 0; j < 4; ++j) {
        a[2 * j]     = fmaf(dw[2 * j],     (float)in.h[j][0], a[2 * j]);
        a[2 * j + 1] = fmaf(dw[2 * j + 1], (float)in.h[j][1], a[2 * j + 1]);
      }
    }
  }
  float s = 0.f, ss = 0.f;
  #pragma unroll
  for (int i = 0; i < 8; ++i) { s += a[i]; ss = fmaf(a[i], a[i], ss); }
  s += __shfl_xor(s, 1);
  ss += __shfl_xor(ss, 1);
  float mean = s * (1.f / 16.f);
  float rstd = rsqrtf(ss * (1.f / 16.f) - mean * mean + EPS);
  const float* ow = olnw + h8 * 8;
  const float* ob = olnb + h8 * 8;
  float r[8];
  #pragma unroll
  for (int i = 0; i < 8; ++i) {
    float t = (a[i] - mean) * rstd * ow[i] + ob[i];
    r[i] = t / (1.f + expf(-t));
  }
  union { uint4 u; h2 h[4]; } o_;
  o_.h[0] = pkrtz(r[0], r[1]); o_.h[1] = pkrtz(r[2], r[3]);
  o_.h[2] = pkrtz(r[4], r[5]); o_.h[3] = pkrtz(r[6], r[7]);
  *(uint4*)(tH + (size_t)pos * 32 + sub * 8) = o_.u;
}

// ---- 16->18 3x3 conv (fp16 in/weights, fdot2) + tanh + abs coords ----------
__global__ __launch_bounds__(256) void k_off(
    const __half* __restrict__ tH, const h2* __restrict__ wT2H,
    const float* __restrict__ offb, float* __restrict__ crd) {
  int tid = blockIdx.x * 128 + (threadIdx.x & 127);  // [0, B*2*16384)
  int h = __builtin_amdgcn_readfirstlane(threadIdx.x >> 7);
  int bg = tid >> 14, rem = tid & 16383;
  int oy = rem >> 7, ox = rem & 127;
  int b = bg >> 1, g = bg & 1;

  float a[9];
  #pragma unroll
  for (int i = 0; i < 9; ++i) a[i] = 0.f;

  #pragma unroll
  for (int kh = 0; kh < 3; ++kh) {
    int ty = oy + kh - 1;
    if (ty < 0 || ty >= 128) continue;
    const __half* base = tH + ((size_t)b * 16384 + (size_t)ty * 128) * 32 + g * 16;
    #pragma unroll
    for (int kw = 0; kw < 3; ++kw) {
      int tap = kh * 3 + kw;
      int tx = ox + kw - 1;
      if ((unsigned)tx >= 128u) continue;
      union { uint4 u[2]; h2 hh[8]; } in;
      const uint4* p = (const uint4*)(base + (size_t)tx * 32);
      in.u[0] = p[0]; in.u[1] = p[1];
      const h2* wrow = wT2H + (size_t)(tap * 2 + h) * 72;
      #pragma unroll
      for (int j2 = 0; j2 < 8; ++j2) {
        h2 f = in.hh[j2];
        #pragma unroll
        for (int i = 0; i < 9; ++i)
          a[i] = fdot2(f, wrow[j2 * 9 + i], a[i]);
      }
    }
  }

  const float* bb = offb + h * 9;
  float* cp = crd + (size_t)tid * 18 + h * 9;
  #pragma unroll
  for (int i = 0; i < 9; ++i) {
    int o = h * 9 + i;
    int kp = o >> 1;
    float basec = (o & 1) ? (float)(kp % 3 - 1 + ox) : (float)(kp / 3 - 1 + oy);
    cp[i] = fmaf(tanhf(a[i] + bb[i]), RANGEF, basec) * RATIO;
  }
}

// ---- FUSED attention v6: qrH pre-scaled fp16, phase A is a raw copy --------
__global__ __launch_bounds__(256) void k_attn2(
    const __half* __restrict__ qrH, const __half* __restrict__ kH,
    const __half* __restrict__ vH, const float* __restrict__ crd,
    const h2* __restrict__ rpbH, float* __restrict__ out) {
  __shared__ __align__(16) h2 qh2S[256];           // 16 pos x 16 h2 (scaled q)
  __shared__ float crdS[576];                      // [g][pos][18]
  __shared__ __align__(16) float4 corn4[576];      // [pos][g][kp][2]
  __shared__ float lgS[576];
  int b = blockIdx.x >> 10;
  int p0 = (blockIdx.x & 1023) * 16;
  const h2* kbase = (const h2*)(kH + (size_t)b * 131072);

  // phase A: stage scaled q (raw 1 KB copy) + crd
  {
    if (threadIdx.x < 64)
      ((uint4*)qh2S)[threadIdx.x] =
          ((const uint4*)(qrH + (size_t)(b * 16384 + p0) * 32))[threadIdx.x];
    if (threadIdx.x < 144) {
      int g = threadIdx.x / 72, i = threadIdx.x - (threadIdx.x / 72) * 72;
      const float4* src = (const float4*)(crd + ((size_t)(b * 2 + g) * 16384 + p0) * 18);
      *(float4*)(crdS + g * 288 + i * 4) = src[i];
    }
  }

  // phase A2 (threads 0..31, barrier-free): kp=8 task per (pos, g).
  if (threadIdx.x < 32) {
    int pl = threadIdx.x >> 1, g = threadIdx.x & 1;
    float2 cc = *(const float2*)(crd +
        ((size_t)(b * 2 + g) * 16384 + p0 + pl) * 18 + 16);
    float wc[4]; int idx[4];
    corners(cc.x, cc.y, wc, idx);

    union { uint4 u[2]; h2 h[8]; } qa;
    const uint4* qg = (const uint4*)(qrH + ((size_t)(b * 16384 + p0 + pl)) * 32 + g * 16);
    qa.u[0] = qg[0]; qa.u[1] = qg[1];

    const h2* kb = kbase + g * 8;
    float a0 = 0.f, a1 = 0.f;
    #pragma unroll
    for (int c = 0; c < 4; ++c) {
      union { float4 f[2]; h2 h[8]; } kk;
      const float4* kr = (const float4*)(kb + (size_t)idx[c] * 16);
      kk.f[0] = kr[0]; kk.f[1] = kr[1];
      float d0 = 0.f, d1 = 0.f;
      #pragma unroll
      for (int j = 0; j < 4; ++j) {
        d0 = fdot2(qa.h[j], kk.h[j], d0);
        d1 = fdot2(qa.h[4 + j], kk.h[4 + j], d1);
      }
      a0 = fmaf(wc[c], d0, a0);
      a1 = fmaf(wc[c], d1, a1);
    }
    const h2* rp0 = rpbH + (2 * g * 9 + 8) * 4;
    const h2* rp1 = rpbH + ((2 * g + 1) * 9 + 8) * 4;
    #pragma unroll
    for (int j = 0; j < 4; ++j) {
      a0 = fdot2(qa.h[j], rp0[j], a0);
      a1 = fdot2(qa.h[4 + j], rp1[j], a1);
    }
    lgS[(pl * 4 + 2 * g) * 9 + 8] = a0;
    lgS[(pl * 4 + 2 * g + 1) * 9 + 8] = a1;
    corn4[((pl * 2 + g) * 9 + 8) * 2 + 0] =
        make_float4(wc[0], __int_as_float(idx[0]), wc[1], __int_as_float(idx[1]));
    corn4[((pl * 2 + g) * 9 + 8) * 2 + 1] =
        make_float4(wc[2], __int_as_float(idx[2]), wc[3], __int_as_float(idx[3]));
  }
  __syncthreads();

  // phase B: exactly 256 tasks = (pos, g, kp 0..7)
  {
    int pl = threadIdx.x >> 4, r = threadIdx.x & 15;
    int g = r >> 3, kp = r & 7;
    float iy = crdS[g * 288 + pl * 18 + 2 * kp];
    float ix = crdS[g * 288 + pl * 18 + 2 * kp + 1];
    float wc[4]; int idx[4];
    corners(iy, ix, wc, idx);

    const h2* qa = qh2S + pl * 16 + g * 8;
    const h2* kb = kbase + g * 8;
    float a0 = 0.f, a1 = 0.f;
    #pragma unroll
    for (int c = 0; c < 4; ++c) {
      union { float4 f[2]; h2 h[8]; } kk;
      const float4* kr = (const float4*)(kb + (size_t)idx[c] * 16);
      kk.f[0] = kr[0]; kk.f[1] = kr[1];
      float d0 = 0.f, d1 = 0.f;
      #pragma unroll
      for (int j = 0; j < 4; ++j) {
        d0 = fdot2(qa[j], kk.h[j], d0);
        d1 = fdot2(qa[4 + j], kk.h[4 + j], d1);
      }
      a0 = fmaf(wc[c], d0, a0);
      a1 = fmaf(wc[c], d1, a1);
    }
    const h2* rp0 = rpbH + (2 * g * 9 + kp) * 4;
    const h2* rp1 = rpbH + ((2 * g + 1) * 9 + kp) * 4;
    #pragma unroll
    for (int j = 0; j < 4; ++j) {
      a0 = fdot2(qa[j], rp0[j], a0);
      a1 = fdot2(qa[4 + j], rp1[j], a1);
    }
    lgS[(pl * 4 + 2 * g) * 9 + kp] = a0;
    lgS[(pl * 4 + 2 * g + 1) * 9 + kp] = a1;
    corn4[((pl * 2 + g) * 9 + kp) * 2 + 0] =
        make_float4(wc[0], __int_as_float(idx[0]), wc[1], __int_as_float(idx[1]));
    corn4[((pl * 2 + g) * 9 + kp) * 2 + 1] =
        make_float4(wc[2], __int_as_float(idx[2]), wc[3], __int_as_float(idx[3]));
  }
  __syncthreads();

  // phase D: per-thread softmax + plain v-gather loop
  int pl = threadIdx.x >> 4, c8 = threadIdx.x & 15;
  int g = c8 >> 3, h = c8 >> 2, ch = c8 * 8;
  int pos = p0 + pl;

  float w9[9];
  {
    const float* l = lgS + (pl * 4 + h) * 9;
    float m = l[0];
    #pragma unroll
    for (int kp = 1; kp < 9; ++kp) m = fmaxf(m, l[kp]);
    float s = 0.f;
    #pragma unroll
    for (int kp = 0; kp < 9; ++kp) { w9[kp] = __expf(l[kp] - m); s += w9[kp]; }
    float inv = 1.f / s;
    #pragma unroll
    for (int kp = 0; kp < 9; ++kp) w9[kp] *= inv;
  }

  const __half* vb = vH + (size_t)b * 524288 + ch;
  const float4* corn = corn4 + (pl * 2 + g) * 18;
  constexpr unsigned SEL_LO = 0x01000504u, SEL_HI = 0x03020706u;

  float acc[8] = {};
  #pragma unroll
  for (int kp = 0; kp < 9; ++kp) {
    float aw = w9[kp];
    float4 ca = corn[kp * 2], cb = corn[kp * 2 + 1];
    #pragma unroll
    for (int pr = 0; pr < 2; ++pr) {
      float4 cp = pr ? cb : ca;
      h2 w01 = pkrtz(aw * cp.x, aw * cp.z);
      uint4 r0 = *(const uint4*)(vb + (size_t)__float_as_int(cp.y) * 128);
      uint4 r1 = *(const uint4*)(vb + (size_t)__float_as_int(cp.w) * 128);
      acc[0] = fdot2(w01, permh(r0.x, r1.x, SEL_LO), acc[0]);
      acc[1] = fdot2(w01, permh(r0.x, r1.x, SEL_HI), acc[1]);
      acc[2] = fdot2(w01, permh(r0.y, r1.y, SEL_LO), acc[2]);
      acc[3] = fdot2(w01, permh(r0.y, r1.y, SEL_HI), acc[3]);
      acc[4] = fdot2(w01, permh(r0.z, r1.z, SEL_LO), acc[4]);
      acc[5] = fdot2(w01, permh(r0.z, r1.z, SEL_HI), acc[5]);
      acc[6] = fdot2(w01, permh(r0.w, r1.w, SEL_LO), acc[6]);
      acc[7] = fdot2(w01, permh(r0.w, r1.w, SEL_HI), acc[7]);
    }
  }

  float* op = out + ((size_t)b * 128 + ch) * 16384 + pos;
  #pragma unroll
  for (int i = 0; i < 8; ++i) op[(size_t)i * 16384] = acc[i];
}

}  // namespace

extern "C" void kernel_launch(void* const* d_in, const int* in_sizes, int n_in,
                              void* d_out, int out_size, void* d_ws, size_t ws_size,
                              hipStream_t stream) {
  const float* x    = (const float*)d_in[0];
  const float* lnw  = (const float*)d_in[1];
  const float* lnb  = (const float*)d_in[2];
  const float* wq   = (const float*)d_in[3];
  const float* wk   = (const float*)d_in[4];
  const float* dww  = (const float*)d_in[5];
  const float* olnw = (const float*)d_in[6];
  const float* olnb = (const float*)d_in[7];
  const float* offw = (const float*)d_in[8];
  const float* offb = (const float*)d_in[9];
  const float* rpb  = (const float*)d_in[10];
  float* outp = (float*)d_out;

  int B = in_sizes[0] / (128 * 64 * 64);
  size_t nb = (size_t)B * 4096;   // input positions
  size_t np = (size_t)B * 16384;  // output positions

  char* w8 = (char*)d_ws;
  __half* vH  = (__half*)w8;  w8 += nb * 128 * 2;
  __half* kH  = (__half*)w8;  w8 += nb * 32 * 2;
  __half* qH  = (__half*)w8;  w8 += nb * 32 * 2;
  __half* qrH = (__half*)w8;  w8 += np * 32 * 2;
  __half* tH  = (__half*)w8;  w8 += np * 32 * 2;
  float*  crd = (float*)w8;   w8 += np * 2 * 18 * 4;
  float*  dwT = (float*)w8;   w8 += 144 * 4;
  h2*     wqH = (h2*)w8;      w8 += 2048 * 4;
  h2*     wkH = (h2*)w8;      w8 += 2048 * 4;
  h2*     wT2H= (h2*)w8;      w8 += 1296 * 4;
  h2*     rpbH= (h2*)w8;      w8 += 1024;

  hipLaunchKernelGGL(k_transpose, dim3(B * 64), dim3(256), 0, stream,
                     x, vH, offw, dww, wq, wk, rpb, wT2H, dwT, wqH, wkH, rpbH);
  hipLaunchKernelGGL(k_lnproj, dim3(B * 256), dim3(256), 0, stream,
                     vH, lnw, lnb, wqH, wkH, qH, kH);
  hipLaunchKernelGGL(k_resize, dim3(B * 256), dim3(256), 0, stream, qH, qrH);
  hipLaunchKernelGGL(k_dwln, dim3(B * 256), dim3(256), 0, stream,
                     qrH, dwT, olnw, olnb, tH);
  hipLaunchKernelGGL(k_off, dim3(B * 256), dim3(256), 0, stream, tH, wT2H, offb, crd);
  hipLaunchKernelGGL(k_attn2, dim3(B * 1024), dim3(256), 0, stream,
                     qrH, kH, vH, crd, rpbH, outp);
}